// Round 2
// baseline (919.374 us; speedup 1.0000x reference)
//
#include <hip/hip_runtime.h>

// ---------------------------------------------------------------------------
// PaiNN interaction layer, fp32.
//   ctx = silu(q@W1+b1)@W2+b2           [N,384]
//   x   = W_ij * ctx[idx_j]             [E,384]  (dq | dmu_r | dmu_mu)
//   dq  = segment_sum(x[:, :128], idx_i)
//   dmu = segment_sum(x_r*dir + x_m*mu[idx_j], idx_i)
//   out = (q+dq, mu+dmu)
// Strategy: CSR sort by idx_i with {e,j} payload (chase depth 1), then
// wave-per-node register accumulation with batch-4 software pipelining.
// ---------------------------------------------------------------------------

typedef float f2 __attribute__((ext_vector_type(2)));

static __host__ __device__ inline size_t ws_align(size_t x) { return (x + 255) & ~(size_t)255; }

// ---------------- GEMM: C[M,Ncols] = act(A[M,128] @ B[128,Ncols] + bias) ----
template <bool SILU>
__global__ __launch_bounds__(256, 2) void gemm_bias_act_kernel(
    const float* __restrict__ A, const float* __restrict__ B,
    const float* __restrict__ bias, float* __restrict__ C,
    int M, int Ncols)
{
    __shared__ float As[128][68];   // transposed A tile: As[k][row]
    __shared__ float Bs[128][68];   // Bs[k][col]

    const int t    = threadIdx.x;
    const int row0 = blockIdx.x * 64;
    const int col0 = blockIdx.y * 64;

    #pragma unroll
    for (int it = 0; it < 8; ++it) {
        int l    = t + 256 * it;
        int r    = l >> 5;
        int k4   = (l & 31) << 2;
        int grow = row0 + r;
        float4 v = make_float4(0.f, 0.f, 0.f, 0.f);
        if (grow < M) v = *reinterpret_cast<const float4*>(A + (size_t)grow * 128 + k4);
        As[k4 + 0][r] = v.x; As[k4 + 1][r] = v.y;
        As[k4 + 2][r] = v.z; As[k4 + 3][r] = v.w;
    }
    #pragma unroll
    for (int it = 0; it < 8; ++it) {
        int l  = t + 256 * it;
        int k  = l >> 4;
        int c4 = (l & 15) << 2;
        float4 v = *reinterpret_cast<const float4*>(B + (size_t)k * Ncols + col0 + c4);
        *reinterpret_cast<float4*>(&Bs[k][c4]) = v;
    }
    __syncthreads();

    const int tx = t & 15, ty = t >> 4;
    float acc[4][4];
    #pragma unroll
    for (int i = 0; i < 4; ++i)
        #pragma unroll
        for (int j = 0; j < 4; ++j) acc[i][j] = 0.f;

    #pragma unroll 4
    for (int k = 0; k < 128; ++k) {
        float4 a = *reinterpret_cast<const float4*>(&As[k][ty * 4]);
        float4 b = *reinterpret_cast<const float4*>(&Bs[k][tx * 4]);
        acc[0][0] += a.x * b.x; acc[0][1] += a.x * b.y; acc[0][2] += a.x * b.z; acc[0][3] += a.x * b.w;
        acc[1][0] += a.y * b.x; acc[1][1] += a.y * b.y; acc[1][2] += a.y * b.z; acc[1][3] += a.y * b.w;
        acc[2][0] += a.z * b.x; acc[2][1] += a.z * b.y; acc[2][2] += a.z * b.z; acc[2][3] += a.z * b.w;
        acc[3][0] += a.w * b.x; acc[3][1] += a.w * b.y; acc[3][2] += a.w * b.z; acc[3][3] += a.w * b.w;
    }

    float4 bv = *reinterpret_cast<const float4*>(bias + col0 + tx * 4);
    #pragma unroll
    for (int i = 0; i < 4; ++i) {
        int grow = row0 + ty * 4 + i;
        if (grow >= M) continue;
        float4 o;
        o.x = acc[i][0] + bv.x; o.y = acc[i][1] + bv.y;
        o.z = acc[i][2] + bv.z; o.w = acc[i][3] + bv.w;
        if (SILU) {
            o.x = o.x / (1.f + __expf(-o.x));
            o.y = o.y / (1.f + __expf(-o.y));
            o.z = o.z / (1.f + __expf(-o.z));
            o.w = o.w / (1.f + __expf(-o.w));
        }
        *reinterpret_cast<float4*>(C + (size_t)grow * Ncols + col0 + tx * 4) = o;
    }
}

// ---------------- CSR build ------------------------------------------------
__global__ void zero_int_kernel(int* __restrict__ p, int n) {
    int i = blockIdx.x * 256 + threadIdx.x;
    if (i < n) p[i] = 0;
}

__global__ void count_kernel(const int* __restrict__ idx_i, int* __restrict__ cnt, int E) {
    int e = blockIdx.x * 256 + threadIdx.x;
    if (e < E) atomicAdd(&cnt[idx_i[e]], 1);
}

// single-block exclusive scan; writes row_ptr[0..N] and (in-place) cursor=cnt array
__global__ __launch_bounds__(256) void scan_kernel(int* __restrict__ cnt_cursor,
                                                   int* __restrict__ row_ptr, int N) {
    __shared__ int sums[256];
    __shared__ int offs[256];
    int t = threadIdx.x;
    int chunk = (N + 255) / 256;
    int lo = t * chunk;
    int hi = lo + chunk; if (hi > N) hi = N; if (lo > N) lo = N;
    int s = 0;
    for (int i = lo; i < hi; ++i) s += cnt_cursor[i];
    sums[t] = s;
    __syncthreads();
    if (t == 0) {
        int acc = 0;
        for (int k = 0; k < 256; ++k) { int v = sums[k]; offs[k] = acc; acc += v; }
    }
    __syncthreads();
    int acc = offs[t];
    for (int i = lo; i < hi; ++i) {
        int v = cnt_cursor[i];       // read count
        cnt_cursor[i] = acc;         // overwrite with exclusive prefix (cursor)
        row_ptr[i]    = acc;
        acc += v;
    }
    if (t == 255) row_ptr[N] = acc;
}

__global__ void fill_kernel(const int* __restrict__ idx_i, const int* __restrict__ idx_j,
                            int* __restrict__ cursor, int2* __restrict__ payload, int E) {
    int e = blockIdx.x * 256 + threadIdx.x;
    if (e < E) {
        int pos = atomicAdd(&cursor[idx_i[e]], 1);
        payload[pos] = make_int2(e, idx_j[e]);
    }
}

// ---------------- node accumulation: one wave per node ---------------------
// lane owns features {2*lane, 2*lane+1}. Batch-4 edge processing: 4 payload
// loads issue in parallel, then ~48 independent data loads, then FMAs.
__global__ __launch_bounds__(256) void node_kernel(
    const float* __restrict__ q, const float* __restrict__ mu,
    const float* __restrict__ ctx, const float* __restrict__ W_ij,
    const float* __restrict__ dir_ij, const int* __restrict__ row_ptr,
    const int2* __restrict__ payload, float* __restrict__ out, int N)
{
    int wid  = (blockIdx.x * blockDim.x + threadIdx.x) >> 6;
    int lane = threadIdx.x & 63;
    if (wid >= N) return;

    int p   = row_ptr[wid];
    int end = row_ptr[wid + 1];
    const int f = lane * 2;

    f2 qa  = {0.f, 0.f};
    f2 ma0 = {0.f, 0.f}, ma1 = {0.f, 0.f}, ma2 = {0.f, 0.f};

    while (p + 4 <= end) {
        int2 pl[4];
        #pragma unroll
        for (int u = 0; u < 4; ++u) pl[u] = payload[p + u];

        f2 wq[4], wr[4], wm[4], cq[4], cr[4], cm[4], m0[4], m1[4], m2[4];
        float d0[4], d1[4], d2[4];
        #pragma unroll
        for (int u = 0; u < 4; ++u) {
            const float* w  = W_ij + (size_t)pl[u].x * 384;
            const float* cj = ctx  + (size_t)pl[u].y * 384;
            const float* mj = mu   + (size_t)pl[u].y * 384;
            wq[u] = __builtin_nontemporal_load(reinterpret_cast<const f2*>(w + f));
            wr[u] = __builtin_nontemporal_load(reinterpret_cast<const f2*>(w + 128 + f));
            wm[u] = __builtin_nontemporal_load(reinterpret_cast<const f2*>(w + 256 + f));
            cq[u] = *reinterpret_cast<const f2*>(cj + f);
            cr[u] = *reinterpret_cast<const f2*>(cj + 128 + f);
            cm[u] = *reinterpret_cast<const f2*>(cj + 256 + f);
            m0[u] = *reinterpret_cast<const f2*>(mj + f);
            m1[u] = *reinterpret_cast<const f2*>(mj + 128 + f);
            m2[u] = *reinterpret_cast<const f2*>(mj + 256 + f);
            d0[u] = __builtin_nontemporal_load(dir_ij + 3 * (size_t)pl[u].x + 0);
            d1[u] = __builtin_nontemporal_load(dir_ij + 3 * (size_t)pl[u].x + 1);
            d2[u] = __builtin_nontemporal_load(dir_ij + 3 * (size_t)pl[u].x + 2);
        }
        #pragma unroll
        for (int u = 0; u < 4; ++u) {
            qa += wq[u] * cq[u];
            f2 xr = wr[u] * cr[u];
            f2 xm = wm[u] * cm[u];
            ma0 += xr * d0[u] + xm * m0[u];
            ma1 += xr * d1[u] + xm * m1[u];
            ma2 += xr * d2[u] + xm * m2[u];
        }
        p += 4;
    }
    while (p < end) {
        int2 pl = payload[p++];
        const float* w  = W_ij + (size_t)pl.x * 384;
        const float* cj = ctx  + (size_t)pl.y * 384;
        const float* mj = mu   + (size_t)pl.y * 384;
        f2 wq = __builtin_nontemporal_load(reinterpret_cast<const f2*>(w + f));
        f2 wr = __builtin_nontemporal_load(reinterpret_cast<const f2*>(w + 128 + f));
        f2 wm = __builtin_nontemporal_load(reinterpret_cast<const f2*>(w + 256 + f));
        f2 cq = *reinterpret_cast<const f2*>(cj + f);
        f2 cr = *reinterpret_cast<const f2*>(cj + 128 + f);
        f2 cm = *reinterpret_cast<const f2*>(cj + 256 + f);
        f2 m0 = *reinterpret_cast<const f2*>(mj + f);
        f2 m1 = *reinterpret_cast<const f2*>(mj + 128 + f);
        f2 m2 = *reinterpret_cast<const f2*>(mj + 256 + f);
        float d0 = __builtin_nontemporal_load(dir_ij + 3 * (size_t)pl.x + 0);
        float d1 = __builtin_nontemporal_load(dir_ij + 3 * (size_t)pl.x + 1);
        float d2 = __builtin_nontemporal_load(dir_ij + 3 * (size_t)pl.x + 2);
        qa += wq * cq;
        f2 xr = wr * cr;
        f2 xm = wm * cm;
        ma0 += xr * d0 + xm * m0;
        ma1 += xr * d1 + xm * m1;
        ma2 += xr * d2 + xm * m2;
    }

    // out_q = q + dq   (q row touched once, streamed -> nontemporal)
    f2 qv = __builtin_nontemporal_load(reinterpret_cast<const f2*>(q + (size_t)wid * 128 + f));
    __builtin_nontemporal_store(qv + qa, reinterpret_cast<f2*>(out + (size_t)wid * 128 + f));

    // out_mu = mu + dmu  (mu is also gathered by other waves -> cached loads)
    const float* mbase = mu + (size_t)wid * 384;
    float* obase = out + (size_t)N * 128 + (size_t)wid * 384;
    f2 mv0 = *reinterpret_cast<const f2*>(mbase + f);
    f2 mv1 = *reinterpret_cast<const f2*>(mbase + 128 + f);
    f2 mv2 = *reinterpret_cast<const f2*>(mbase + 256 + f);
    __builtin_nontemporal_store(mv0 + ma0, reinterpret_cast<f2*>(obase + f));
    __builtin_nontemporal_store(mv1 + ma1, reinterpret_cast<f2*>(obase + 128 + f));
    __builtin_nontemporal_store(mv2 + ma2, reinterpret_cast<f2*>(obase + 256 + f));
}

// ---------------------------------------------------------------------------
extern "C" void kernel_launch(void* const* d_in, const int* in_sizes, int n_in,
                              void* d_out, int out_size, void* d_ws, size_t ws_size,
                              hipStream_t stream) {
    const float* q      = (const float*)d_in[0];
    const float* mu     = (const float*)d_in[1];
    const float* W_ij   = (const float*)d_in[2];
    const float* dir_ij = (const float*)d_in[3];
    const float* W1     = (const float*)d_in[4];
    const float* b1     = (const float*)d_in[5];
    const float* W2     = (const float*)d_in[6];
    const float* b2     = (const float*)d_in[7];
    const int*   idx_i  = (const int*)d_in[8];
    const int*   idx_j  = (const int*)d_in[9];

    const int N = in_sizes[0] / 128;     // 20000
    const int E = in_sizes[8];           // 320000
    float* out = (float*)d_out;

    // workspace carve-up
    char* ws = (char*)d_ws;
    size_t off = 0;
    float* ctx     = (float*)(ws + off); off += ws_align((size_t)N * 384 * 4);
    float* h       = (float*)(ws + off); off += ws_align((size_t)N * 128 * 4);
    int*   row_ptr = (int*)  (ws + off); off += ws_align((size_t)(N + 1) * 4);
    int*   cursor  = (int*)  (ws + off); off += ws_align((size_t)N * 4);
    int2*  payload = (int2*) (ws + off); off += ws_align((size_t)E * 8);
    (void)ws_size; (void)n_in; (void)out_size;

    const int nblk_rows = (N + 63) / 64;
    const int eblk = (E + 255) / 256;
    const int nblk = (N + 255) / 256;

    // context net
    gemm_bias_act_kernel<true ><<<dim3(nblk_rows, 2), 256, 0, stream>>>(q, W1, b1, h,   N, 128);
    gemm_bias_act_kernel<false><<<dim3(nblk_rows, 6), 256, 0, stream>>>(h, W2, b2, ctx, N, 384);

    // CSR build (sort edges by destination idx_i); payload = {e, j}
    zero_int_kernel<<<nblk, 256, 0, stream>>>(cursor, N);
    count_kernel<<<eblk, 256, 0, stream>>>(idx_i, cursor, E);
    scan_kernel<<<1, 256, 0, stream>>>(cursor, row_ptr, N);
    fill_kernel<<<eblk, 256, 0, stream>>>(idx_i, idx_j, cursor, payload, E);

    // per-node register accumulation + fused output add (no fp32 atomics)
    node_kernel<<<(N + 3) / 4, 256, 0, stream>>>(q, mu, ctx, W_ij, dir_ij,
                                                 row_ptr, payload, out, N);
}

// Round 3
// 918.412 us; speedup vs baseline: 1.0010x; 1.0010x over previous
//
#include <hip/hip_runtime.h>

// ---------------------------------------------------------------------------
// PaiNN interaction layer, fp32.
//   ctx = silu(q@W1+b1)@W2+b2           [N,384]
//   x   = W_ij * ctx[idx_j]             [E,384]  (dq | dmu_r | dmu_mu)
//   dq  = segment_sum(x[:, :128], idx_i)
//   dmu = segment_sum(x_r*dir + x_m*mu[idx_j], idx_i)
//   out = (q+dq, mu+dmu)
// Strategy: CSR sort by idx_i with {e,j} payload; wave-per-node accumulation.
// Wave layout: half-wave (32 lanes) x float4 covers one 128-f segment; the
// two halves process two different edges of the same node concurrently, so
// every global load is a coalesced 512B dwordx4 burst. Cross-half shfl_xor
// combines partials; output rows split across halves.
// ---------------------------------------------------------------------------

typedef float f4 __attribute__((ext_vector_type(4)));

static __host__ __device__ inline size_t ws_align(size_t x) { return (x + 255) & ~(size_t)255; }

// ---------------- GEMM: C[M,Ncols] = act(A[M,128] @ B[128,Ncols] + bias) ----
template <bool SILU>
__global__ __launch_bounds__(256, 2) void gemm_bias_act_kernel(
    const float* __restrict__ A, const float* __restrict__ B,
    const float* __restrict__ bias, float* __restrict__ C,
    int M, int Ncols)
{
    __shared__ float As[128][68];   // transposed A tile: As[k][row]
    __shared__ float Bs[128][68];   // Bs[k][col]

    const int t    = threadIdx.x;
    const int row0 = blockIdx.x * 64;
    const int col0 = blockIdx.y * 64;

    #pragma unroll
    for (int it = 0; it < 8; ++it) {
        int l    = t + 256 * it;
        int r    = l >> 5;
        int k4   = (l & 31) << 2;
        int grow = row0 + r;
        float4 v = make_float4(0.f, 0.f, 0.f, 0.f);
        if (grow < M) v = *reinterpret_cast<const float4*>(A + (size_t)grow * 128 + k4);
        As[k4 + 0][r] = v.x; As[k4 + 1][r] = v.y;
        As[k4 + 2][r] = v.z; As[k4 + 3][r] = v.w;
    }
    #pragma unroll
    for (int it = 0; it < 8; ++it) {
        int l  = t + 256 * it;
        int k  = l >> 4;
        int c4 = (l & 15) << 2;
        float4 v = *reinterpret_cast<const float4*>(B + (size_t)k * Ncols + col0 + c4);
        *reinterpret_cast<float4*>(&Bs[k][c4]) = v;
    }
    __syncthreads();

    const int tx = t & 15, ty = t >> 4;
    float acc[4][4];
    #pragma unroll
    for (int i = 0; i < 4; ++i)
        #pragma unroll
        for (int j = 0; j < 4; ++j) acc[i][j] = 0.f;

    #pragma unroll 4
    for (int k = 0; k < 128; ++k) {
        float4 a = *reinterpret_cast<const float4*>(&As[k][ty * 4]);
        float4 b = *reinterpret_cast<const float4*>(&Bs[k][tx * 4]);
        acc[0][0] += a.x * b.x; acc[0][1] += a.x * b.y; acc[0][2] += a.x * b.z; acc[0][3] += a.x * b.w;
        acc[1][0] += a.y * b.x; acc[1][1] += a.y * b.y; acc[1][2] += a.y * b.z; acc[1][3] += a.y * b.w;
        acc[2][0] += a.z * b.x; acc[2][1] += a.z * b.y; acc[2][2] += a.z * b.z; acc[2][3] += a.z * b.w;
        acc[3][0] += a.w * b.x; acc[3][1] += a.w * b.y; acc[3][2] += a.w * b.z; acc[3][3] += a.w * b.w;
    }

    float4 bv = *reinterpret_cast<const float4*>(bias + col0 + tx * 4);
    #pragma unroll
    for (int i = 0; i < 4; ++i) {
        int grow = row0 + ty * 4 + i;
        if (grow >= M) continue;
        float4 o;
        o.x = acc[i][0] + bv.x; o.y = acc[i][1] + bv.y;
        o.z = acc[i][2] + bv.z; o.w = acc[i][3] + bv.w;
        if (SILU) {
            o.x = o.x / (1.f + __expf(-o.x));
            o.y = o.y / (1.f + __expf(-o.y));
            o.z = o.z / (1.f + __expf(-o.z));
            o.w = o.w / (1.f + __expf(-o.w));
        }
        *reinterpret_cast<float4*>(C + (size_t)grow * Ncols + col0 + tx * 4) = o;
    }
}

// ---------------- CSR build ------------------------------------------------
__global__ void zero_int_kernel(int* __restrict__ p, int n) {
    int i = blockIdx.x * 256 + threadIdx.x;
    if (i < n) p[i] = 0;
}

__global__ void count_kernel(const int* __restrict__ idx_i, int* __restrict__ cnt, int E) {
    int e = blockIdx.x * 256 + threadIdx.x;
    if (e < E) atomicAdd(&cnt[idx_i[e]], 1);
}

// single-block exclusive scan; writes row_ptr[0..N] and (in-place) cursor
__global__ __launch_bounds__(256) void scan_kernel(int* __restrict__ cnt_cursor,
                                                   int* __restrict__ row_ptr, int N) {
    __shared__ int sums[256];
    __shared__ int offs[256];
    int t = threadIdx.x;
    int chunk = (N + 255) / 256;
    int lo = t * chunk;
    int hi = lo + chunk; if (hi > N) hi = N; if (lo > N) lo = N;
    int s = 0;
    for (int i = lo; i < hi; ++i) s += cnt_cursor[i];
    sums[t] = s;
    __syncthreads();
    if (t == 0) {
        int acc = 0;
        for (int k = 0; k < 256; ++k) { int v = sums[k]; offs[k] = acc; acc += v; }
    }
    __syncthreads();
    int acc = offs[t];
    for (int i = lo; i < hi; ++i) {
        int v = cnt_cursor[i];
        cnt_cursor[i] = acc;
        row_ptr[i]    = acc;
        acc += v;
    }
    if (t == 255) row_ptr[N] = acc;
}

__global__ void fill_kernel(const int* __restrict__ idx_i, const int* __restrict__ idx_j,
                            int* __restrict__ cursor, int2* __restrict__ payload, int E) {
    int e = blockIdx.x * 256 + threadIdx.x;
    if (e < E) {
        int pos = atomicAdd(&cursor[idx_i[e]], 1);
        payload[pos] = make_int2(e, idx_j[e]);
    }
}

// ---------------- node accumulation: one wave per node ---------------------
struct EdgeRegs { f4 wq, wr, wm, cq, cr, cm, m0, m1, m2; float d0, d1, d2; };

__device__ __forceinline__ EdgeRegs load_edge(
    const float* __restrict__ W_ij, const float* __restrict__ ctx,
    const float* __restrict__ mu, const float* __restrict__ dir_ij,
    int2 pl, int fb)
{
    EdgeRegs r;
    const float* w  = W_ij + (size_t)pl.x * 384 + fb;
    const float* cj = ctx  + (size_t)pl.y * 384 + fb;
    const float* mj = mu   + (size_t)pl.y * 384 + fb;
    const float* dp = dir_ij + 3 * (size_t)pl.x;
    r.wq = __builtin_nontemporal_load(reinterpret_cast<const f4*>(w));
    r.wr = __builtin_nontemporal_load(reinterpret_cast<const f4*>(w + 128));
    r.wm = __builtin_nontemporal_load(reinterpret_cast<const f4*>(w + 256));
    r.cq = *reinterpret_cast<const f4*>(cj);
    r.cr = *reinterpret_cast<const f4*>(cj + 128);
    r.cm = *reinterpret_cast<const f4*>(cj + 256);
    r.m0 = *reinterpret_cast<const f4*>(mj);
    r.m1 = *reinterpret_cast<const f4*>(mj + 128);
    r.m2 = *reinterpret_cast<const f4*>(mj + 256);
    r.d0 = __builtin_nontemporal_load(dp + 0);
    r.d1 = __builtin_nontemporal_load(dp + 1);
    r.d2 = __builtin_nontemporal_load(dp + 2);
    return r;
}

__device__ __forceinline__ void accum(const EdgeRegs& r, f4& qa, f4& ma0, f4& ma1, f4& ma2) {
    qa += r.wq * r.cq;
    f4 xr = r.wr * r.cr;
    f4 xm = r.wm * r.cm;
    ma0 += xr * r.d0 + xm * r.m0;
    ma1 += xr * r.d1 + xm * r.m1;
    ma2 += xr * r.d2 + xm * r.m2;
}

__global__ __launch_bounds__(256, 3) void node_kernel(
    const float* __restrict__ q, const float* __restrict__ mu,
    const float* __restrict__ ctx, const float* __restrict__ W_ij,
    const float* __restrict__ dir_ij, const int* __restrict__ row_ptr,
    const int2* __restrict__ payload, float* __restrict__ out, int N)
{
    int wid  = (blockIdx.x * blockDim.x + threadIdx.x) >> 6;
    int lane = threadIdx.x & 63;
    if (wid >= N) return;

    int p   = row_ptr[wid];
    int end = row_ptr[wid + 1];
    const int half = lane >> 5;          // which edge of the pair this lane works
    const int fb   = (lane & 31) << 2;   // feature base: 32 lanes x 4 = 128

    f4 qa  = {0.f, 0.f, 0.f, 0.f};
    f4 ma0 = qa, ma1 = qa, ma2 = qa;

    // 4 edges per iteration (2 pairs in flight for MLP)
    while (p + 4 <= end) {
        int2 pl0 = payload[p + half];
        int2 pl1 = payload[p + 2 + half];
        EdgeRegs r0 = load_edge(W_ij, ctx, mu, dir_ij, pl0, fb);
        EdgeRegs r1 = load_edge(W_ij, ctx, mu, dir_ij, pl1, fb);
        accum(r0, qa, ma0, ma1, ma2);
        accum(r1, qa, ma0, ma1, ma2);
        p += 4;
    }
    if (p + 2 <= end) {
        int2 pl = payload[p + half];
        EdgeRegs r = load_edge(W_ij, ctx, mu, dir_ij, pl, fb);
        accum(r, qa, ma0, ma1, ma2);
        p += 2;
    }
    if (p < end && half == 0) {          // single tail edge on half 0
        int2 pl = payload[p];
        EdgeRegs r = load_edge(W_ij, ctx, mu, dir_ij, pl, fb);
        accum(r, qa, ma0, ma1, ma2);
    }

    // combine the two half-wave partials (all lanes end with full sums)
    #pragma unroll
    for (int c = 0; c < 4; ++c) {
        qa[c]  += __shfl_xor(qa[c],  32);
        ma0[c] += __shfl_xor(ma0[c], 32);
        ma1[c] += __shfl_xor(ma1[c], 32);
        ma2[c] += __shfl_xor(ma2[c], 32);
    }

    // split the 4 output rows across halves; each store = 32 lanes x 16B
    const float* mbase = mu  + (size_t)wid * 384;
    const float* qrow  = q   + (size_t)wid * 128;
    float* obase = out + (size_t)N * 128 + (size_t)wid * 384;
    float* oqrow = out + (size_t)wid * 128;

    const float* inA = half ? mbase         : qrow;
    const float* inB = half ? (mbase + 256) : (mbase + 128);
    float*       oA  = half ? obase         : oqrow;
    float*       oB  = half ? (obase + 256) : (obase + 128);
    f4 sA = half ? ma0 : qa;
    f4 sB = half ? ma2 : ma1;

    f4 vA = *reinterpret_cast<const f4*>(inA + fb);
    f4 vB = *reinterpret_cast<const f4*>(inB + fb);
    __builtin_nontemporal_store(vA + sA, reinterpret_cast<f4*>(oA + fb));
    __builtin_nontemporal_store(vB + sB, reinterpret_cast<f4*>(oB + fb));
}

// ---------------------------------------------------------------------------
extern "C" void kernel_launch(void* const* d_in, const int* in_sizes, int n_in,
                              void* d_out, int out_size, void* d_ws, size_t ws_size,
                              hipStream_t stream) {
    const float* q      = (const float*)d_in[0];
    const float* mu     = (const float*)d_in[1];
    const float* W_ij   = (const float*)d_in[2];
    const float* dir_ij = (const float*)d_in[3];
    const float* W1     = (const float*)d_in[4];
    const float* b1     = (const float*)d_in[5];
    const float* W2     = (const float*)d_in[6];
    const float* b2     = (const float*)d_in[7];
    const int*   idx_i  = (const int*)d_in[8];
    const int*   idx_j  = (const int*)d_in[9];

    const int N = in_sizes[0] / 128;     // 20000
    const int E = in_sizes[8];           // 320000
    float* out = (float*)d_out;

    // workspace carve-up
    char* ws = (char*)d_ws;
    size_t off = 0;
    float* ctx     = (float*)(ws + off); off += ws_align((size_t)N * 384 * 4);
    float* h       = (float*)(ws + off); off += ws_align((size_t)N * 128 * 4);
    int*   row_ptr = (int*)  (ws + off); off += ws_align((size_t)(N + 1) * 4);
    int*   cursor  = (int*)  (ws + off); off += ws_align((size_t)N * 4);
    int2*  payload = (int2*) (ws + off); off += ws_align((size_t)E * 8);
    (void)ws_size; (void)n_in; (void)out_size;

    const int nblk_rows = (N + 63) / 64;
    const int eblk = (E + 255) / 256;
    const int nblk = (N + 255) / 256;

    // context net
    gemm_bias_act_kernel<true ><<<dim3(nblk_rows, 2), 256, 0, stream>>>(q, W1, b1, h,   N, 128);
    gemm_bias_act_kernel<false><<<dim3(nblk_rows, 6), 256, 0, stream>>>(h, W2, b2, ctx, N, 384);

    // CSR build (sort edges by destination idx_i); payload = {e, j}
    zero_int_kernel<<<nblk, 256, 0, stream>>>(cursor, N);
    count_kernel<<<eblk, 256, 0, stream>>>(idx_i, cursor, E);
    scan_kernel<<<1, 256, 0, stream>>>(cursor, row_ptr, N);
    fill_kernel<<<eblk, 256, 0, stream>>>(idx_i, idx_j, cursor, payload, E);

    // per-node register accumulation + fused output add (no fp32 atomics)
    node_kernel<<<(N + 3) / 4, 256, 0, stream>>>(q, mu, ctx, W_ij, dir_ij,
                                                 row_ptr, payload, out, N);
}